// Round 3
// baseline (839.441 us; speedup 1.0000x reference)
//
#include <hip/hip_runtime.h>
#include <stdint.h>

#define KDIM  4096    // contraction dim (cols of attention, rows of h)
#define NROWS 16384   // C*N rows of attention
#define INF   512
#define OUTF  128

typedef short bf16x8 __attribute__((ext_vector_type(8)));
typedef float f32x4  __attribute__((ext_vector_type(4)));
typedef unsigned short u16;

// ---- workspace layout (bytes), all 16B-aligned ----
#define WS_LEAF 0                         // 524288 f32 numpy-pairwise leaf sums
#define WS_SUB  2097152                   // 512 f32 subtree sums
#define WS_MEAN 2099200                   // 1 f32 (padded to 16)
#define WS_ZP   2099216                   // 8*4096 f32 Z partials
#define WS_RSZ  2230288                   // 4096 f32 (2.5/Z)
#define WS_H2P  2246672                   // 4096*128 bf16: h in MFMA-B layout
#define WS_PART 3295248                   // K-split fp32 partials
#define PART_STRIDE ((size_t)NROWS*OUTF)  // floats per K-split slab (8 MB)

__device__ __forceinline__ u16 f32_to_bf16_rne(float f){
  unsigned u = __float_as_uint(f);
  unsigned r = u + 0x7fffu + ((u >> 16) & 1u);
  return (u16)(r >> 16);
}

__device__ __forceinline__ bf16x8 cvt8(float4 a, float4 b){
  bf16x8 r;
  r[0]=(short)f32_to_bf16_rne(a.x); r[1]=(short)f32_to_bf16_rne(a.y);
  r[2]=(short)f32_to_bf16_rne(a.z); r[3]=(short)f32_to_bf16_rne(a.w);
  r[4]=(short)f32_to_bf16_rne(b.x); r[5]=(short)f32_to_bf16_rne(b.y);
  r[6]=(short)f32_to_bf16_rne(b.z); r[7]=(short)f32_to_bf16_rne(b.w);
  return r;
}

// ---- K1a: numpy-pairwise leaf sums. Leaf = 128 consecutive elements,
// 8 independent chains (stride 8, serial order), combined ((r0+r1)+(r2+r3))+((r4+r5)+(r6+r7)).
// 8 threads per leaf, one chain each; shfl-xor tree = exact numpy combine order.
__global__ void __launch_bounds__(256) k_leaf(const float* __restrict__ att,
                                              float* __restrict__ leaf){
  int gid = blockIdx.x*256 + threadIdx.x;   // 0..4194303
  int lf = gid >> 3, k = gid & 7;
  const float* p = att + (size_t)lf*128 + k;
  float r = p[0];
  #pragma unroll
  for (int j = 1; j < 16; ++j) r += p[j*8];
  r += __shfl_xor(r, 1);
  r += __shfl_xor(r, 2);
  r += __shfl_xor(r, 4);
  if (k == 0) leaf[lf] = r;
}

// ---- K1b: pairwise-reduce 1024 consecutive leaves per block (10 exact levels)
__global__ void __launch_bounds__(256) k_tree1(const float* __restrict__ leaf,
                                               float* __restrict__ sub){
  __shared__ float A[1024], B[512];
  int b = blockIdx.x;
  for (int i = threadIdx.x; i < 1024; i += 256) A[i] = leaf[(size_t)b*1024 + i];
  __syncthreads();
  for (int i = threadIdx.x; i < 512; i += 256) B[i] = A[2*i] + A[2*i+1];
  __syncthreads();
  if (threadIdx.x < 256) A[threadIdx.x] = B[2*threadIdx.x] + B[2*threadIdx.x+1];
  __syncthreads();
  int n = 128; float* src = A; float* dst = B;
  while (n >= 1){
    if (threadIdx.x < n) dst[threadIdx.x] = src[2*threadIdx.x] + src[2*threadIdx.x+1];
    __syncthreads();
    float* t = src; src = dst; dst = t; n >>= 1;
  }
  if (threadIdx.x == 0) sub[b] = src[0];
}

// ---- K1c: pairwise-reduce 512 subtree sums (9 exact levels) -> mean
__global__ void __launch_bounds__(256) k_tree2(const float* __restrict__ sub,
                                               float* __restrict__ meanv){
  __shared__ float A[512], B[256];
  for (int i = threadIdx.x; i < 512; i += 256) A[i] = sub[i];
  __syncthreads();
  int n = 256; float* src = A; float* dst = B;
  while (n >= 1){
    if (threadIdx.x < n) dst[threadIdx.x] = src[2*threadIdx.x] + src[2*threadIdx.x+1];
    __syncthreads();
    float* t = src; src = dst; dst = t; n >>= 1;
  }
  if (threadIdx.x == 0) meanv[0] = src[0] * (1.0f/67108864.0f);  // /2^26 exact
}

// ---- K2: per-column Z partials (8 row-splits of 2048 rows) ---------------
__global__ void __launch_bounds__(256) k_z(const float* __restrict__ att,
                                           const float* __restrict__ meanv,
                                           float* __restrict__ Zp){
  const float mean = meanv[0];
  const int cb = blockIdx.x & 63;       // column block (64 cols)
  const int rs = blockIdx.x >> 6;       // row split
  const int r0 = threadIdx.x >> 4;      // 0..15
  const int c4 = threadIdx.x & 15;      // 0..15
  const int col = cb*64 + c4*4;
  float a0=0.f, a1=0.f, a2=0.f, a3=0.f;
  for (int it = 0; it < 128; ++it){
    int row = rs*2048 + it*16 + r0;
    float4 v = *(const float4*)(att + (size_t)row*KDIM + col);
    a0 += (v.x > mean) ? __expf(v.x) : 0.f;
    a1 += (v.y > mean) ? __expf(v.y) : 0.f;
    a2 += (v.z > mean) ? __expf(v.z) : 0.f;
    a3 += (v.w > mean) ? __expf(v.w) : 0.f;
  }
  __shared__ float lds[16][68];
  lds[r0][c4*4+0]=a0; lds[r0][c4*4+1]=a1; lds[r0][c4*4+2]=a2; lds[r0][c4*4+3]=a3;
  __syncthreads();
  if (threadIdx.x < 64){
    float s = 0.f;
    #pragma unroll
    for (int r = 0; r < 16; ++r) s += lds[r][threadIdx.x];
    Zp[(size_t)rs*KDIM + cb*64 + threadIdx.x] = s;
  }
}

// ---- K2b: rsZ = 2.5 / sum(Zp)  (1/(1-p_drop) folded in) -----------------
__global__ void k_rsz(const float* __restrict__ Zp, float* __restrict__ rsZ){
  int i = blockIdx.x*256 + threadIdx.x;
  if (i < KDIM){
    float s = 0.f;
    #pragma unroll
    for (int rs = 0; rs < 8; ++rs) s += Zp[(size_t)rs*KDIM + i];
    rsZ[i] = 2.5f / s;
  }
}

// ---- K3: h = x @ W^T (f32 in, bf16 MFMA), stored in MFMA-B-frag layout --
// h2p flat: ((j>>5)*8 + nt)*512 + (((j>>3)&3)*16 + (f&15))*8 + (j&7)
__global__ void __launch_bounds__(256) k_h(const float* __restrict__ x,
                                           const float* __restrict__ W,
                                           u16* __restrict__ h2p){
  const int wave = threadIdx.x >> 6, l = threadIdx.x & 63;
  const int rt = blockIdx.x*4 + wave;   // rows 16rt..16rt+15 of x
  const int m = l & 15, q = l >> 4;
  f32x4 acc[8];
  #pragma unroll
  for (int nt = 0; nt < 8; ++nt) acc[nt] = (f32x4){0.f,0.f,0.f,0.f};
  for (int kb = 0; kb < 16; ++kb){
    const float* xp = x + (size_t)(rt*16+m)*INF + kb*32 + q*8;
    bf16x8 af = cvt8(*(const float4*)xp, *(const float4*)(xp+4));
    #pragma unroll
    for (int nt = 0; nt < 8; ++nt){
      const float* wp = W + (size_t)(nt*16+m)*INF + kb*32 + q*8;
      bf16x8 bf = cvt8(*(const float4*)wp, *(const float4*)(wp+4));
      acc[nt] = __builtin_amdgcn_mfma_f32_16x16x32_bf16(af, bf, acc[nt], 0,0,0);
    }
  }
  #pragma unroll
  for (int nt = 0; nt < 8; ++nt)
    #pragma unroll
    for (int r = 0; r < 4; ++r){
      int j = rt*16 + q*4 + r;                 // row of h (0..4095)
      int kb2 = j >> 5, lane_t = ((j>>3)&3)*16 + m, ii = j & 7;
      h2p[(size_t)(kb2*8 + nt)*512 + lane_t*8 + ii] = f32_to_bf16_rne(acc[nt][r]);
    }
}

// ---- K4: h_prime = a @ h, A generated on the fly ------------------------
__device__ __forceinline__ bf16x8 make_afrag(float4 fl, float4 fh, int4 ma, int4 mb,
                                             float4 za, float4 zb, float mean){
  float w0 = (fl.x > mean && ma.x != 0) ? __expf(fl.x)*za.x : 0.f;
  float w1 = (fl.y > mean && ma.y != 0) ? __expf(fl.y)*za.y : 0.f;
  float w2 = (fl.z > mean && ma.z != 0) ? __expf(fl.z)*za.z : 0.f;
  float w3 = (fl.w > mean && ma.w != 0) ? __expf(fl.w)*za.w : 0.f;
  float w4 = (fh.x > mean && mb.x != 0) ? __expf(fh.x)*zb.x : 0.f;
  float w5 = (fh.y > mean && mb.y != 0) ? __expf(fh.y)*zb.y : 0.f;
  float w6 = (fh.z > mean && mb.z != 0) ? __expf(fh.z)*zb.z : 0.f;
  float w7 = (fh.w > mean && mb.w != 0) ? __expf(fh.w)*zb.w : 0.f;
  bf16x8 r;
  r[0]=(short)f32_to_bf16_rne(w0); r[1]=(short)f32_to_bf16_rne(w1);
  r[2]=(short)f32_to_bf16_rne(w2); r[3]=(short)f32_to_bf16_rne(w3);
  r[4]=(short)f32_to_bf16_rne(w4); r[5]=(short)f32_to_bf16_rne(w5);
  r[6]=(short)f32_to_bf16_rne(w6); r[7]=(short)f32_to_bf16_rne(w7);
  return r;
}

template<int S>
__global__ void __launch_bounds__(256,2) k_mm(const float* __restrict__ att,
    const int* __restrict__ mask, const float* __restrict__ meanv,
    const float* __restrict__ rsZ, const u16* __restrict__ h2p,
    float* __restrict__ part, float* __restrict__ out){
  const float mean = meanv[0];
  const int gw = blockIdx.x*4 + (threadIdx.x >> 6);
  const int rp = gw & 511;            // 32-row group of attention
  const int kh = gw >> 9;             // K-split index
  const int l = threadIdx.x & 63, m = l & 15, q = l >> 4;
  const int KB = 128 / S;
  const int kb0 = kh * KB;
  const size_t ro0 = (size_t)(rp*32 + m) * KDIM;
  const size_t ro1 = ro0 + (size_t)16 * KDIM;
  f32x4 acc[2][8];
  #pragma unroll
  for (int rt = 0; rt < 2; ++rt)
    #pragma unroll
    for (int nt = 0; nt < 8; ++nt) acc[rt][nt] = (f32x4){0.f,0.f,0.f,0.f};

  #pragma unroll 2
  for (int kb = kb0; kb < kb0 + KB; ++kb){
    const int kc = kb*32 + q*8;
    float4 a0l = *(const float4*)(att + ro0 + kc);
    float4 a0h = *(const float4*)(att + ro0 + kc + 4);
    float4 a1l = *(const float4*)(att + ro1 + kc);
    float4 a1h = *(const float4*)(att + ro1 + kc + 4);
    int4 m0l = *(const int4*)(mask + ro0 + kc);
    int4 m0h = *(const int4*)(mask + ro0 + kc + 4);
    int4 m1l = *(const int4*)(mask + ro1 + kc);
    int4 m1h = *(const int4*)(mask + ro1 + kc + 4);
    float4 za = *(const float4*)(rsZ + kc);
    float4 zb = *(const float4*)(rsZ + kc + 4);
    bf16x8 a0 = make_afrag(a0l, a0h, m0l, m0h, za, zb, mean);
    bf16x8 a1 = make_afrag(a1l, a1h, m1l, m1h, za, zb, mean);
    const u16* bp = h2p + (size_t)(kb*8)*512 + l*8;
    #pragma unroll
    for (int nt = 0; nt < 8; ++nt){
      bf16x8 b = *(const bf16x8*)(bp + nt*512);
      acc[0][nt] = __builtin_amdgcn_mfma_f32_16x16x32_bf16(a0, b, acc[0][nt], 0,0,0);
      acc[1][nt] = __builtin_amdgcn_mfma_f32_16x16x32_bf16(a1, b, acc[1][nt], 0,0,0);
    }
  }

  if (S == 1){
    #pragma unroll
    for (int rt = 0; rt < 2; ++rt)
      #pragma unroll
      for (int nt = 0; nt < 8; ++nt)
        #pragma unroll
        for (int r = 0; r < 4; ++r){
          int i = rp*32 + rt*16 + q*4 + r;     // h_prime row
          int f = nt*16 + m;
          out[(size_t)(i & 4095)*512 + (i >> 12)*128 + f] = acc[rt][nt][r];
        }
  } else {
    float* pb = part + (size_t)kh * PART_STRIDE;
    #pragma unroll
    for (int rt = 0; rt < 2; ++rt)
      #pragma unroll
      for (int nt = 0; nt < 8; ++nt)
        #pragma unroll
        for (int r = 0; r < 4; ++r){
          int i = rp*32 + rt*16 + q*4 + r;
          int f = nt*16 + m;
          pb[(size_t)i*128 + f] = acc[rt][nt][r];
        }
  }
}

// ---- K5: reduce K-splits + reorder to (N, C*F) --------------------------
template<int S>
__global__ void __launch_bounds__(256) k_red(const float* __restrict__ part,
                                             float* __restrict__ out){
  int g = blockIdx.x*256 + threadIdx.x;   // 524288 groups of 4 floats
  int i = g >> 5;                          // h_prime row
  int fo = (g & 31) << 2;
  const float* p = part + (size_t)i*128 + fo;
  float4 s = *(const float4*)p;
  #pragma unroll
  for (int kh = 1; kh < S; ++kh){
    float4 t = *(const float4*)(p + (size_t)kh * PART_STRIDE);
    s.x += t.x; s.y += t.y; s.z += t.z; s.w += t.w;
  }
  int n = i & 4095, c = i >> 12;
  *(float4*)(out + (size_t)n*512 + c*128 + fo) = s;
}

extern "C" void kernel_launch(void* const* d_in, const int* in_sizes, int n_in,
                              void* d_out, int out_size, void* d_ws, size_t ws_size,
                              hipStream_t stream) {
  const float* x    = (const float*)d_in[0];   // f32 [4096,512]
  const float* att  = (const float*)d_in[1];   // f32 [16384,4096]
  const float* W    = (const float*)d_in[2];   // f32 [128,512]
  const int*   mask = (const int*)d_in[3];     // int 0/1 [16384,4096]
  float* out = (float*)d_out;                  // f32 [4096,512]

  char* ws = (char*)d_ws;
  float* leaf  = (float*)(ws + WS_LEAF);
  float* sub   = (float*)(ws + WS_SUB);
  float* meanv = (float*)(ws + WS_MEAN);
  float* Zp    = (float*)(ws + WS_ZP);
  float* rsZ   = (float*)(ws + WS_RSZ);
  u16*   h2p   = (u16*)(ws + WS_H2P);
  float* part  = (float*)(ws + WS_PART);

  int S = 1;
  if (ws_size >= (size_t)WS_PART + 4ull*PART_STRIDE*4ull) S = 4;
  else if (ws_size >= (size_t)WS_PART + 2ull*PART_STRIDE*4ull) S = 2;

  k_leaf <<<16384, 256, 0, stream>>>(att, leaf);
  k_tree1<<<512,   256, 0, stream>>>(leaf, sub);
  k_tree2<<<1,     256, 0, stream>>>(sub, meanv);
  k_z    <<<512,   256, 0, stream>>>(att, meanv, Zp);
  k_rsz  <<<16,    256, 0, stream>>>(Zp, rsZ);
  k_h    <<<64,    256, 0, stream>>>(x, W, h2p);

  switch (S){
    case 4:
      k_mm<4><<<512, 256, 0, stream>>>(att, mask, meanv, rsZ, h2p, part, out);
      k_red<4><<<2048, 256, 0, stream>>>(part, out);
      break;
    case 2:
      k_mm<2><<<256, 256, 0, stream>>>(att, mask, meanv, rsZ, h2p, part, out);
      k_red<2><<<2048, 256, 0, stream>>>(part, out);
      break;
    default:
      k_mm<1><<<128, 256, 0, stream>>>(att, mask, meanv, rsZ, h2p, part, out);
      break;
  }
}

// Round 4
// 727.655 us; speedup vs baseline: 1.1536x; 1.1536x over previous
//
#include <hip/hip_runtime.h>
#include <stdint.h>

#define KDIM  4096    // contraction dim (cols of attention, rows of h)
#define NROWS 16384   // C*N rows of attention
#define INF   512
#define OUTF  128

typedef short bf16x8 __attribute__((ext_vector_type(8)));
typedef float f32x4  __attribute__((ext_vector_type(4)));
typedef unsigned short u16;

// ---- workspace layout (bytes). Persistent first; transients overlay part.
#define WS_MEAN 0                          // 16 B
#define WS_RSZ  16                         // 4096 f32
#define WS_H2P  16400                      // 4096*128 bf16 (1 MB), B-frag layout
#define WS_PART 1064976                    // K-split fp32 partials (S x 8 MB)
#define WS_LEAF WS_PART                    // transient: 524288 f32 (2 MB)
#define WS_SUB  (WS_PART + 2097152)        // transient: 512 f32
#define WS_ZP   (WS_PART + 2099200)        // transient: 32*4096 f32 (512 KB)
#define PART_STRIDE ((size_t)NROWS*OUTF)   // floats per K-split slab (8 MB)

__device__ __forceinline__ u16 f32_to_bf16_rne(float f){
  unsigned u = __float_as_uint(f);
  unsigned r = u + 0x7fffu + ((u >> 16) & 1u);
  return (u16)(r >> 16);
}

// ---- K1a: numpy-pairwise leaf sums, 1 thread per 128-element leaf -------
// 8 chains (stride 8, serial order), combine ((c0+c1)+(c2+c3))+((c4+c5)+(c6+c7))
__global__ void __launch_bounds__(256) k_leaf(const float* __restrict__ att,
                                              float* __restrict__ leaf){
  int lf = blockIdx.x*256 + threadIdx.x;   // 0..524287
  const float* p = att + (size_t)lf*128;
  float4 u = *(const float4*)p;
  float4 v = *(const float4*)(p + 4);
  float c0=u.x, c1=u.y, c2=u.z, c3=u.w, c4=v.x, c5=v.y, c6=v.z, c7=v.w;
  #pragma unroll
  for (int j = 1; j < 16; ++j){
    float4 a = *(const float4*)(p + j*8);
    float4 b = *(const float4*)(p + j*8 + 4);
    c0+=a.x; c1+=a.y; c2+=a.z; c3+=a.w;
    c4+=b.x; c5+=b.y; c6+=b.z; c7+=b.w;
  }
  leaf[lf] = ((c0+c1)+(c2+c3)) + ((c4+c5)+(c6+c7));
}

// ---- K1b: pairwise-reduce 1024 consecutive leaves per block -------------
__global__ void __launch_bounds__(256) k_tree1(const float* __restrict__ leaf,
                                               float* __restrict__ sub){
  __shared__ float A[1024], B[512];
  int b = blockIdx.x;
  for (int i = threadIdx.x; i < 1024; i += 256) A[i] = leaf[(size_t)b*1024 + i];
  __syncthreads();
  for (int i = threadIdx.x; i < 512; i += 256) B[i] = A[2*i] + A[2*i+1];
  __syncthreads();
  if (threadIdx.x < 256) A[threadIdx.x] = B[2*threadIdx.x] + B[2*threadIdx.x+1];
  __syncthreads();
  int n = 128; float* src = A; float* dst = B;
  while (n >= 1){
    if (threadIdx.x < n) dst[threadIdx.x] = src[2*threadIdx.x] + src[2*threadIdx.x+1];
    __syncthreads();
    float* t = src; src = dst; dst = t; n >>= 1;
  }
  if (threadIdx.x == 0) sub[b] = src[0];
}

// ---- K1c: pairwise-reduce 512 subtree sums -> mean ----------------------
__global__ void __launch_bounds__(256) k_tree2(const float* __restrict__ sub,
                                               float* __restrict__ meanv){
  __shared__ float A[512], B[256];
  for (int i = threadIdx.x; i < 512; i += 256) A[i] = sub[i];
  __syncthreads();
  int n = 256; float* src = A; float* dst = B;
  while (n >= 1){
    if (threadIdx.x < n) dst[threadIdx.x] = src[2*threadIdx.x] + src[2*threadIdx.x+1];
    __syncthreads();
    float* t = src; src = dst; dst = t; n >>= 1;
  }
  if (threadIdx.x == 0) meanv[0] = src[0] * (1.0f/67108864.0f);
}

// ---- K2: per-column Z partials, streaming (32 row-splits x 64 col-stripes)
__global__ void __launch_bounds__(256) k_zf(const float* __restrict__ att,
                                            const float* __restrict__ meanv,
                                            float* __restrict__ Zp){
  const float mean = meanv[0];
  const int sb = blockIdx.x & 63;       // col stripe (64 cols)
  const int rs = blockIdx.x >> 6;       // row split (512 rows)
  const int c8 = threadIdx.x & 7;       // 8 cols per thread
  const int r  = threadIdx.x >> 3;      // 0..31
  const int col = sb*64 + c8*8;
  float a0=0.f,a1=0.f,a2=0.f,a3=0.f,a4=0.f,a5=0.f,a6=0.f,a7=0.f;
  #pragma unroll 2
  for (int it = 0; it < 16; ++it){
    int row = rs*512 + it*32 + r;
    const float* p = att + (size_t)row*KDIM + col;
    float4 u = *(const float4*)p;
    float4 v = *(const float4*)(p + 4);
    a0 += (u.x > mean) ? __expf(u.x) : 0.f;
    a1 += (u.y > mean) ? __expf(u.y) : 0.f;
    a2 += (u.z > mean) ? __expf(u.z) : 0.f;
    a3 += (u.w > mean) ? __expf(u.w) : 0.f;
    a4 += (v.x > mean) ? __expf(v.x) : 0.f;
    a5 += (v.y > mean) ? __expf(v.y) : 0.f;
    a6 += (v.z > mean) ? __expf(v.z) : 0.f;
    a7 += (v.w > mean) ? __expf(v.w) : 0.f;
  }
  __shared__ float lds[32][72];
  lds[r][c8*8+0]=a0; lds[r][c8*8+1]=a1; lds[r][c8*8+2]=a2; lds[r][c8*8+3]=a3;
  lds[r][c8*8+4]=a4; lds[r][c8*8+5]=a5; lds[r][c8*8+6]=a6; lds[r][c8*8+7]=a7;
  __syncthreads();
  if (threadIdx.x < 64){
    float s = 0.f;
    #pragma unroll
    for (int rr = 0; rr < 32; ++rr) s += lds[rr][threadIdx.x];
    Zp[(size_t)rs*KDIM + sb*64 + threadIdx.x] = s;
  }
}

// ---- K2b: rsZ = 2.5 / sum(Zp) -------------------------------------------
__global__ void k_rsz(const float* __restrict__ Zp, float* __restrict__ rsZ){
  int i = blockIdx.x*256 + threadIdx.x;
  if (i < KDIM){
    float s = 0.f;
    #pragma unroll
    for (int rs = 0; rs < 32; ++rs) s += Zp[(size_t)rs*KDIM + i];
    rsZ[i] = 2.5f / s;
  }
}

// ---- K3: h2p[j][f] = bf16( rsZ[j] * (x @ W^T)[j][f] ), B-frag layout ----
__device__ __forceinline__ bf16x8 cvt8(float4 a, float4 b){
  bf16x8 r;
  r[0]=(short)f32_to_bf16_rne(a.x); r[1]=(short)f32_to_bf16_rne(a.y);
  r[2]=(short)f32_to_bf16_rne(a.z); r[3]=(short)f32_to_bf16_rne(a.w);
  r[4]=(short)f32_to_bf16_rne(b.x); r[5]=(short)f32_to_bf16_rne(b.y);
  r[6]=(short)f32_to_bf16_rne(b.z); r[7]=(short)f32_to_bf16_rne(b.w);
  return r;
}

__global__ void __launch_bounds__(256) k_h(const float* __restrict__ x,
                                           const float* __restrict__ W,
                                           const float* __restrict__ rsZ,
                                           u16* __restrict__ h2p){
  const int wave = threadIdx.x >> 6, l = threadIdx.x & 63;
  const int rt = blockIdx.x*4 + wave;   // rows 16rt..16rt+15 of x
  const int m = l & 15, q = l >> 4;
  f32x4 acc[8];
  #pragma unroll
  for (int nt = 0; nt < 8; ++nt) acc[nt] = (f32x4){0.f,0.f,0.f,0.f};
  for (int kb = 0; kb < 16; ++kb){
    const float* xp = x + (size_t)(rt*16+m)*INF + kb*32 + q*8;
    bf16x8 af = cvt8(*(const float4*)xp, *(const float4*)(xp+4));
    #pragma unroll
    for (int nt = 0; nt < 8; ++nt){
      const float* wp = W + (size_t)(nt*16+m)*INF + kb*32 + q*8;
      bf16x8 bf = cvt8(*(const float4*)wp, *(const float4*)(wp+4));
      acc[nt] = __builtin_amdgcn_mfma_f32_16x16x32_bf16(af, bf, acc[nt], 0,0,0);
    }
  }
  float4 rz = *(const float4*)(rsZ + rt*16 + q*4);   // rsZ[j], j = rt*16+q*4+r
  float rzv[4] = {rz.x, rz.y, rz.z, rz.w};
  #pragma unroll
  for (int nt = 0; nt < 8; ++nt)
    #pragma unroll
    for (int r = 0; r < 4; ++r){
      int j = rt*16 + q*4 + r;                 // row of h (0..4095)
      int kb2 = j >> 5, lane_t = ((j>>3)&3)*16 + m, ii = j & 7;
      h2p[(size_t)(kb2*8 + nt)*512 + lane_t*8 + ii] =
          f32_to_bf16_rne(acc[nt][r] * rzv[r]);
    }
}

// ---- K4: h_prime = a @ h2p, A generated on the fly, 2-stage SW pipeline -
__device__ __forceinline__ bf16x8 make_afrag(float4 fl, float4 fh, int4 ma, int4 mb,
                                             float mean){
  float w0 = (fl.x > mean && ma.x != 0) ? __expf(fl.x) : 0.f;
  float w1 = (fl.y > mean && ma.y != 0) ? __expf(fl.y) : 0.f;
  float w2 = (fl.z > mean && ma.z != 0) ? __expf(fl.z) : 0.f;
  float w3 = (fl.w > mean && ma.w != 0) ? __expf(fl.w) : 0.f;
  float w4 = (fh.x > mean && mb.x != 0) ? __expf(fh.x) : 0.f;
  float w5 = (fh.y > mean && mb.y != 0) ? __expf(fh.y) : 0.f;
  float w6 = (fh.z > mean && mb.z != 0) ? __expf(fh.z) : 0.f;
  float w7 = (fh.w > mean && mb.w != 0) ? __expf(fh.w) : 0.f;
  bf16x8 r;
  r[0]=(short)f32_to_bf16_rne(w0); r[1]=(short)f32_to_bf16_rne(w1);
  r[2]=(short)f32_to_bf16_rne(w2); r[3]=(short)f32_to_bf16_rne(w3);
  r[4]=(short)f32_to_bf16_rne(w4); r[5]=(short)f32_to_bf16_rne(w5);
  r[6]=(short)f32_to_bf16_rne(w6); r[7]=(short)f32_to_bf16_rne(w7);
  return r;
}

template<int S>
__global__ void __launch_bounds__(256,2) k_mm(const float* __restrict__ att,
    const int* __restrict__ mask, const float* __restrict__ meanv,
    const u16* __restrict__ h2p, float* __restrict__ part,
    float* __restrict__ out){
  const float mean = meanv[0];
  const int gw = blockIdx.x*4 + (threadIdx.x >> 6);
  const int rp = gw & 511;            // 32-row group of attention
  const int kh = gw >> 9;             // K-split index
  const int l = threadIdx.x & 63, m = l & 15, q = l >> 4;
  const int KB = 128 / S;
  const int kb0 = kh * KB;
  const size_t ro0 = (size_t)(rp*32 + m) * KDIM;
  const size_t ro1 = ro0 + (size_t)16 * KDIM;
  f32x4 acc[2][8];
  #pragma unroll
  for (int rt = 0; rt < 2; ++rt)
    #pragma unroll
    for (int nt = 0; nt < 8; ++nt) acc[rt][nt] = (f32x4){0.f,0.f,0.f,0.f};

  // two register stages
  float4 A0l[2], A0h[2], A1l[2], A1h[2];
  int4   M0l[2], M0h[2], M1l[2], M1h[2];
  bf16x8 Bv[2][8];

#define LOADSTAGE(kb_, s_) {                                                  \
    const int kc = (kb_)*32 + q*8;                                            \
    A0l[s_] = *(const float4*)(att + ro0 + kc);                               \
    A0h[s_] = *(const float4*)(att + ro0 + kc + 4);                           \
    A1l[s_] = *(const float4*)(att + ro1 + kc);                               \
    A1h[s_] = *(const float4*)(att + ro1 + kc + 4);                           \
    M0l[s_] = *(const int4*)(mask + ro0 + kc);                                \
    M0h[s_] = *(const int4*)(mask + ro0 + kc + 4);                            \
    M1l[s_] = *(const int4*)(mask + ro1 + kc);                                \
    M1h[s_] = *(const int4*)(mask + ro1 + kc + 4);                            \
    const u16* bp_ = h2p + (size_t)((kb_)*8)*512 + l*8;                       \
    _Pragma("unroll")                                                         \
    for (int nt = 0; nt < 8; ++nt) Bv[s_][nt] = *(const bf16x8*)(bp_ + nt*512); }

#define COMPSTAGE(s_) {                                                       \
    bf16x8 a0 = make_afrag(A0l[s_], A0h[s_], M0l[s_], M0h[s_], mean);         \
    bf16x8 a1 = make_afrag(A1l[s_], A1h[s_], M1l[s_], M1h[s_], mean);         \
    _Pragma("unroll")                                                         \
    for (int nt = 0; nt < 8; ++nt){                                           \
      acc[0][nt] = __builtin_amdgcn_mfma_f32_16x16x32_bf16(a0, Bv[s_][nt], acc[0][nt], 0,0,0); \
      acc[1][nt] = __builtin_amdgcn_mfma_f32_16x16x32_bf16(a1, Bv[s_][nt], acc[1][nt], 0,0,0); } }

  LOADSTAGE(kb0, 0);
  int kb = kb0;
  for (; kb + 2 < kb0 + KB; kb += 2){
    LOADSTAGE(kb+1, 1);
    COMPSTAGE(0);
    LOADSTAGE(kb+2, 0);
    COMPSTAGE(1);
  }
  LOADSTAGE(kb0 + KB - 1, 1);
  COMPSTAGE(0);
  COMPSTAGE(1);
#undef LOADSTAGE
#undef COMPSTAGE

  if (S == 1){
    #pragma unroll
    for (int rt = 0; rt < 2; ++rt)
      #pragma unroll
      for (int nt = 0; nt < 8; ++nt)
        #pragma unroll
        for (int r = 0; r < 4; ++r){
          int i = rp*32 + rt*16 + q*4 + r;     // h_prime row
          int f = nt*16 + m;
          out[(size_t)(i & 4095)*512 + (i >> 12)*128 + f] = acc[rt][nt][r];
        }
  } else {
    float* pb = part + (size_t)kh * PART_STRIDE;
    #pragma unroll
    for (int rt = 0; rt < 2; ++rt)
      #pragma unroll
      for (int nt = 0; nt < 8; ++nt)
        #pragma unroll
        for (int r = 0; r < 4; ++r){
          int i = rp*32 + rt*16 + q*4 + r;
          int f = nt*16 + m;
          pb[(size_t)i*128 + f] = acc[rt][nt][r];
        }
  }
}

// ---- K5: reduce K-splits + reorder to (N, C*F) --------------------------
template<int S>
__global__ void __launch_bounds__(256) k_red(const float* __restrict__ part,
                                             float* __restrict__ out){
  int g = blockIdx.x*256 + threadIdx.x;   // 524288 groups of 4 floats
  int i = g >> 5;                          // h_prime row
  int fo = (g & 31) << 2;
  const float* p = part + (size_t)i*128 + fo;
  float4 s = *(const float4*)p;
  #pragma unroll
  for (int kh = 1; kh < S; ++kh){
    float4 t = *(const float4*)(p + (size_t)kh * PART_STRIDE);
    s.x += t.x; s.y += t.y; s.z += t.z; s.w += t.w;
  }
  int n = i & 4095, c = i >> 12;
  *(float4*)(out + (size_t)n*512 + c*128 + fo) = s;
}

extern "C" void kernel_launch(void* const* d_in, const int* in_sizes, int n_in,
                              void* d_out, int out_size, void* d_ws, size_t ws_size,
                              hipStream_t stream) {
  const float* x    = (const float*)d_in[0];   // f32 [4096,512]
  const float* att  = (const float*)d_in[1];   // f32 [16384,4096]
  const float* W    = (const float*)d_in[2];   // f32 [128,512]
  const int*   mask = (const int*)d_in[3];     // int 0/1 [16384,4096]
  float* out = (float*)d_out;                  // f32 [4096,512]

  char* ws = (char*)d_ws;
  float* meanv = (float*)(ws + WS_MEAN);
  float* rsZ   = (float*)(ws + WS_RSZ);
  u16*   h2p   = (u16*)(ws + WS_H2P);
  float* part  = (float*)(ws + WS_PART);
  float* leaf  = (float*)(ws + WS_LEAF);   // transient overlays of part
  float* sub   = (float*)(ws + WS_SUB);
  float* Zp    = (float*)(ws + WS_ZP);

  int S = 1;
  if (ws_size >= (size_t)WS_PART + 4ull*PART_STRIDE*4ull) S = 4;
  else if (ws_size >= (size_t)WS_PART + 2ull*PART_STRIDE*4ull) S = 2;

  k_leaf <<<2048, 256, 0, stream>>>(att, leaf);
  k_tree1<<<512,  256, 0, stream>>>(leaf, sub);
  k_tree2<<<1,    256, 0, stream>>>(sub, meanv);
  k_zf   <<<2048, 256, 0, stream>>>(att, meanv, Zp);
  k_rsz  <<<16,   256, 0, stream>>>(Zp, rsZ);
  k_h    <<<64,   256, 0, stream>>>(x, W, rsZ, h2p);

  switch (S){
    case 4:
      k_mm<4><<<512, 256, 0, stream>>>(att, mask, meanv, h2p, part, out);
      k_red<4><<<2048, 256, 0, stream>>>(part, out);
      break;
    case 2:
      k_mm<2><<<256, 256, 0, stream>>>(att, mask, meanv, h2p, part, out);
      k_red<2><<<2048, 256, 0, stream>>>(part, out);
      break;
    default:
      k_mm<1><<<128, 256, 0, stream>>>(att, mask, meanv, h2p, part, out);
      break;
  }
}